// Round 12
// baseline (103.547 us; speedup 1.0000x reference)
//
#include <hip/hip_runtime.h>
#include <math.h>

#define T_STEPS 256
#define BATCH   128
#define DIMD    512
#define NROWS   (T_STEPS * BATCH)   // 32768
#define PF      16                  // rolling prefetch depth / chunk size
#define NCHUNK  (T_STEPS / PF)      // 16
#define WRITER_BLOCKS 258
#define GEMV_BLOCKS 1024            // 32 rows/block, 8 rows/wave
#define CNT_TARGET  64              // gemv blocks per chunk
#define GRID (2 + WRITER_BLOCKS + GEMV_BLOCKS)   // 1284

#define INV2PI  0.15915494309189535f
#define L2E     1.4426950408889634f
#define TWO_L2E 2.8853900817779268f

#define AGENT __HIP_MEMORY_SCOPE_AGENT

typedef float f32x4 __attribute__((ext_vector_type(4)));

#if __has_builtin(__builtin_amdgcn_sinf)
#define HW_SIN(x) __builtin_amdgcn_sinf(x)   // sin(2*pi*x), x in revolutions
#else
__device__ __forceinline__ float HW_SIN(float x) { return __sinf(x * 6.283185307179586f); }
#endif
#if __has_builtin(__builtin_amdgcn_exp2f)
#define EXP2(x) __builtin_amdgcn_exp2f(x)
#else
#define EXP2(x) exp2f(x)
#endif
#if __has_builtin(__builtin_amdgcn_rcpf)
#define RCP(x) __builtin_amdgcn_rcpf(x)
#else
#define RCP(x) (1.0f / (x))
#endif

// Agent-scope relaxed ops (sc-flagged; straight to coherence point, no
// wbl2/inv cache maintenance — R4 lesson). Rare polls only — R5 lesson.
__device__ __forceinline__ void  st_rlx(float* p, float v) {
    __hip_atomic_store(p, v, __ATOMIC_RELAXED, AGENT);
}
__device__ __forceinline__ float ld_rlx(const float* p) {
    return __hip_atomic_load(p, __ATOMIC_RELAXED, AGENT);
}
__device__ __forceinline__ void  st_rlx_i(int* p, int v) {
    __hip_atomic_store(p, v, __ATOMIC_RELAXED, AGENT);
}
__device__ __forceinline__ int   ld_rlx_i(const int* p) {
    return __hip_atomic_load(p, __ATOMIC_RELAXED, AGENT);
}
#define VMFENCE() asm volatile("s_waitcnt vmcnt(0)" ::: "memory")
#define CFENCE()  asm volatile("" ::: "memory")

// ---------------------------------------------------------------------------
// mega: bid 0 = qconsts (zero-LDS, 1 wave per gate); bid 1 = scan;
// bids 2..259 = writers; bids 260.. = gemv (chunk-ordered producers).
// ---------------------------------------------------------------------------
__global__ __launch_bounds__(256) void mega(
    const float* __restrict__ inp,
    const float* __restrict__ Wf, const float* __restrict__ Wi,
    const float* __restrict__ Wg, const float* __restrict__ Wo,
    const float* __restrict__ bfp, const float* __restrict__ bip,
    const float* __restrict__ bgp, const float* __restrict__ bop,
    const float* __restrict__ Pf, const float* __restrict__ Pi,
    const float* __restrict__ Pg, const float* __restrict__ Po,
    float4* __restrict__ out4,
    float4* __restrict__ X4, float* __restrict__ Hs,
    float* __restrict__ cfin, float* __restrict__ gc,
    int* __restrict__ qflag, int* __restrict__ hProg, int* __restrict__ cnt)
{
    const int bid  = blockIdx.x;
    const int tid  = threadIdx.x;
    const int wv   = tid >> 6;
    const int lane = tid & 63;

    if (bid == 0) {
        // ========= qconsts: zero-LDS, wave g handles gate g =========
        const int g = wv;
        const float* P = (g == 0) ? Pf : (g == 1) ? Pi : (g == 2) ? Pg : Po;
        const float* W = (g == 0) ? Wf : (g == 1) ? Wi : (g == 2) ? Wg : Wo;

        // amplitude k = 64*j + lane, j=0..3; two state vectors (cols 0,128)
        float v0r[4], v0i[4], v1r[4], v1i[4];
#pragma unroll
        for (int j = 0; j < 4; ++j) {
            const int k = 64 * j + lane;
            v0r[j] = (k == 0)   ? 1.0f : 0.0f;  v0i[j] = 0.0f;
            v1r[j] = (k == 128) ? 1.0f : 0.0f;  v1i[j] = 0.0f;
        }

        for (int l = 0; l < 2; ++l) {
            for (int w = 0; w < 8; ++w) {
                const float phi = P[l * 24 + w * 3 + 0];
                const float th  = P[l * 24 + w * 3 + 1];
                const float om  = P[l * 24 + w * 3 + 2];
                float sh, chh; __sincosf(0.5f * th, &sh, &chh);
                float sp, cp;  __sincosf(0.5f * (phi + om), &sp, &cp);
                float sm, cm;  __sincosf(0.5f * (phi - om), &sm, &cm);
                const float m00r =  cp * chh, m00i = -sp * chh;
                const float m01r = -cm * sh,  m01i = -sm * sh;
                const float m10r =  cm * sh,  m10i = -sm * sh;
                const float m11r =  cp * chh, m11i =  sp * chh;

                const int shift = 7 - w;

                float o0r[4], o0i[4], o1r[4], o1i[4];
#pragma unroll
                for (int j = 0; j < 4; ++j) {
                    o0r[j] = v0r[j]; o0i[j] = v0i[j];
                    o1r[j] = v1r[j]; o1i[j] = v1i[j];
                }
#pragma unroll
                for (int j = 0; j < 4; ++j) {
                    float a0r, a0i, a1r, a1i, b0r, b0i, b1r, b1i;
                    int bit;
                    if (shift <= 5) {
                        const int m = 1 << shift;
                        const float p0r = __shfl_xor(o0r[j], m);
                        const float p0i = __shfl_xor(o0i[j], m);
                        const float p1r = __shfl_xor(o1r[j], m);
                        const float p1i = __shfl_xor(o1i[j], m);
                        bit = (lane >> shift) & 1;
                        a0r = bit ? p0r : o0r[j];  a0i = bit ? p0i : o0i[j];
                        a1r = bit ? o0r[j] : p0r;  a1i = bit ? o0i[j] : p0i;
                        b0r = bit ? p1r : o1r[j];  b0i = bit ? p1i : o1i[j];
                        b1r = bit ? o1r[j] : p1r;  b1i = bit ? o1i[j] : p1i;
                    } else {
                        const int j0 = (shift == 6) ? (j & ~1) : (j & ~2);
                        const int j1 = (shift == 6) ? (j | 1)  : (j | 2);
                        bit = (shift == 6) ? (j & 1) : (j >> 1);
                        a0r = o0r[j0]; a0i = o0i[j0]; a1r = o0r[j1]; a1i = o0i[j1];
                        b0r = o1r[j0]; b0i = o1i[j0]; b1r = o1r[j1]; b1i = o1i[j1];
                    }
                    const float mr0 = bit ? m10r : m00r, mi0 = bit ? m10i : m00i;
                    const float mr1 = bit ? m11r : m01r, mi1 = bit ? m11i : m01i;
                    v0r[j] = mr0 * a0r - mi0 * a0i + mr1 * a1r - mi1 * a1i;
                    v0i[j] = mr0 * a0i + mi0 * a0r + mr1 * a1i + mi1 * a1r;
                    v1r[j] = mr0 * b0r - mi0 * b0i + mr1 * b1r - mi1 * b1i;
                    v1i[j] = mr0 * b0i + mi0 * b0r + mr1 * b1i + mi1 * b1r;
                }
            }
            // CNOT chain permutation (gather via variable shfl)
            float o0r[4], o0i[4], o1r[4], o1i[4];
#pragma unroll
            for (int j = 0; j < 4; ++j) {
                o0r[j] = v0r[j]; o0i[j] = v0i[j];
                o1r[j] = v1r[j]; o1i[j] = v1i[j];
            }
#pragma unroll
            for (int j = 0; j < 4; ++j) {
                int src = 64 * j + lane;
                for (int w = 6; w >= 0; --w) {
                    const int cb = (src >> (7 - w)) & 1;
                    src ^= cb << (6 - w);
                }
                const int sl = src & 63, sj = src >> 6;
                float r0r = 0, r0i = 0, r1r = 0, r1i = 0;
#pragma unroll
                for (int jj = 0; jj < 4; ++jj) {
                    const float t0r = __shfl(o0r[jj], sl);
                    const float t0i = __shfl(o0i[jj], sl);
                    const float t1r = __shfl(o1r[jj], sl);
                    const float t1i = __shfl(o1i[jj], sl);
                    if (sj == jj) { r0r = t0r; r0i = t0i; r1r = t1r; r1i = t1i; }
                }
                v0r[j] = r0r; v0i[j] = r0i; v1r[j] = r1r; v1i[j] = r1i;
            }
        }

        float t00 = 0, t11 = 0, t01 = 0;
#pragma unroll
        for (int j = 0; j < 4; ++j) {
            const float z = (j < 2) ? 1.0f : -1.0f;
            t00 += z * (v0r[j] * v0r[j] + v0i[j] * v0i[j]);
            t11 += z * (v1r[j] * v1r[j] + v1i[j] * v1i[j]);
            t01 += z * (v0i[j] * v1r[j] - v0r[j] * v1i[j]);
        }
        float tsw = 0;
#pragma unroll
        for (int jj = 0; jj < 8; ++jj) tsw += W[512 + lane + 64 * jj];

        for (int off = 32; off; off >>= 1) {
            t00 += __shfl_xor(t00, off);
            t11 += __shfl_xor(t11, off);
            t01 += __shfl_xor(t01, off);
            tsw += __shfl_xor(tsw, off);
        }
        if (lane == 0) {
            const float A  = 0.5f * (t00 + t11);
            const float Bc = 0.5f * (t00 - t11);
            const float Bs = -t01;
            const float R  = sqrtf(Bc * Bc + Bs * Bs);
            const float ph = atan2f(Bc, Bs) * INV2PI;
            const float sc = (g == 2) ? TWO_L2E : -L2E;
            st_rlx(&gc[4 * g + 0], sc * A);
            st_rlx(&gc[4 * g + 1], sc * R);
            st_rlx(&gc[4 * g + 2], ph);
            st_rlx(&gc[4 * g + 3], tsw * INV2PI);
        }
        VMFENCE();
        __syncthreads();
        if (tid == 0) st_rlx_i(qflag, 1);
        return;
    }

    if (bid == 1) {
        // ========= scan: 128 chains, rolling prefetch, chunk gating =========
        if (tid >= BATCH) return;
        const int b = tid;
        const int wv2 = tid >> 6;

        while (ld_rlx_i(qflag) == 0) __builtin_amdgcn_s_sleep(2);
        CFENCE();
        float gcl[16];
#pragma unroll
        for (int j = 0; j < 16; ++j) gcl[j] = ld_rlx(&gc[j]);
        const float Af = gcl[0],  Rf = gcl[1],  phf = gcl[2],  swf = gcl[3];
        const float Ai = gcl[4],  Ri = gcl[5],  phi_ = gcl[6], swi = gcl[7];
        const float Ag = gcl[8],  Rg = gcl[9],  phg = gcl[10], swg = gcl[11];
        const float Ao = gcl[12], Ro = gcl[13], pho = gcl[14], swo = gcl[15];

        while (ld_rlx_i(&cnt[0]) < CNT_TARGET) __builtin_amdgcn_s_sleep(4);
        CFENCE();

        float4 p[PF];
#pragma unroll
        for (int j = 0; j < PF; ++j) {
            const float4 v = X4[j * BATCH + b];
            p[j] = make_float4(v.x + phf, v.y + phi_, v.z + phg, v.w + pho);
        }

        bool allDone = false;
        float c = 0.0f, h = 0.0f;
        for (int k = 0; k < NCHUNK; ++k) {
            const int tb = k * PF;
            // gate chunk k+1 before its rows get touched by rolling refills;
            // once gemv is fully done, stop polling (no more vmcnt drains).
            if (k < NCHUNK - 1 && !allDone) {
                while (ld_rlx_i(&cnt[k + 1]) < CNT_TARGET)
                    __builtin_amdgcn_s_sleep(4);
                allDone = (ld_rlx_i(&cnt[NCHUNK - 1]) >= CNT_TARGET);
                CFENCE();
            }
#pragma unroll
            for (int j = 0; j < PF; ++j) {
                const int t = tb + j;
                const float4 xv = p[j];
                {   // branchless rolling refill PF ahead (pad covers tail)
                    const float4 v = X4[(t + PF) * BATCH + b];
                    p[j] = make_float4(v.x + phf, v.y + phi_,
                                       v.z + phg, v.w + pho);
                }
                const float thf = fmaf(h, swf, xv.x);
                const float thi = fmaf(h, swi, xv.y);
                const float thg = fmaf(h, swg, xv.z);
                const float tho = fmaf(h, swo, xv.w);
                const float ef = EXP2(fmaf(Rf, HW_SIN(thf), Af));
                const float ei = EXP2(fmaf(Ri, HW_SIN(thi), Ai));
                const float eg = EXP2(fmaf(Rg, HW_SIN(thg), Ag));
                const float eo = EXP2(fmaf(Ro, HW_SIN(tho), Ao));
                const float Ff = ef + 1.0f, Fi = ei + 1.0f;
                const float Fg = eg + 1.0f, Fo = eo + 1.0f;
                const float FiFg = Fi * Fg;
                const float num  = fmaf(c, FiFg, (eg - 1.0f) * Ff);
                c = num * RCP(Ff * FiFg);                    // single rcp
                const float ec = EXP2(c * TWO_L2E);
                h = (ec - 1.0f) * RCP(Fo * (ec + 1.0f));     // o*tanh(c)
                st_rlx(&Hs[t * BATCH + b], h);
            }
            if (k == NCHUNK - 1) st_rlx(&cfin[b], c);
            if ((k & 3) == 3) {            // publish at t = 64,128,192,256
                VMFENCE();
                if (lane == 0) st_rlx_i(&hProg[wv2], tb + PF);
            }
        }
        return;
    }

    if (bid < 2 + WRITER_BLOCKS) {
        // ========= writers: t = bid-2, one quarter per wave =========
        const int t  = bid - 2;           // 0..257 (256=hx, 257=cx)
        const int qd = wv;
        const int pidx = (qd < 2) ? 0 : 1;
        const int need = (t < 256) ? ((t >> 6) + 1) << 6 : 256;

        int cur = ld_rlx_i(&hProg[pidx]);
        while (cur < need) {
            int loops = ((need - cur) >> 5) + 1;
            for (int s = 0; s < loops; ++s) {
                __builtin_amdgcn_s_sleep(32);
                __builtin_amdgcn_s_sleep(32);
            }
            cur = ld_rlx_i(&hProg[pidx]);
        }
        CFENCE();

        const float* src = (t == 257) ? cfin
                         : (Hs + ((t >= 256 ? 255 : t) * BATCH));
        const float hv = src[qd * 32 + (lane & 31)];

        size_t base = (t < 256) ? ((size_t)t * 16384)
                    : (t == 256 ? (size_t)4194304 : (size_t)4210688);
        base += (size_t)qd * 4096;
#pragma unroll 8
        for (int j = 0; j < 64; ++j) {
            const float v = __shfl(hv, j >> 1);
            const f32x4 val = {v, v, v, v};
            __builtin_nontemporal_store(val, (f32x4*)(out4 + base + j * 64 + lane));
        }
        return;
    }

    // ========= gemv: 8 rows per wave, chunk-ordered, publishes cnt =========
    const int gb = bid - (2 + WRITER_BLOCKS);       // 0..1023
    const int rowbase = gb * 32 + wv * 8;

    const float4* wfp = (const float4*)Wf;
    const float4* wip = (const float4*)Wi;
    const float4* wgp = (const float4*)Wg;
    const float4* wop = (const float4*)Wo;
    const float4 fa = wfp[lane], fb = wfp[lane + 64];
    const float4 ia = wip[lane], ib = wip[lane + 64];
    const float4 ga = wgp[lane], gb4 = wgp[lane + 64];
    const float4 oa = wop[lane], ob = wop[lane + 64];

    const float4* xr = (const float4*)(inp + (size_t)rowbase * DIMD);
    float sums[8][4];   // [row][gate]
#pragma unroll
    for (int r = 0; r < 8; ++r) {
        const float4 xa = xr[r * 128 + lane];
        const float4 xb = xr[r * 128 + lane + 64];
        sums[r][0] = xa.x * fa.x + xa.y * fa.y + xa.z * fa.z + xa.w * fa.w
                   + xb.x * fb.x + xb.y * fb.y + xb.z * fb.z + xb.w * fb.w;
        sums[r][1] = xa.x * ia.x + xa.y * ia.y + xa.z * ia.z + xa.w * ia.w
                   + xb.x * ib.x + xb.y * ib.y + xb.z * ib.z + xb.w * ib.w;
        sums[r][2] = xa.x * ga.x + xa.y * ga.y + xa.z * ga.z + xa.w * ga.w
                   + xb.x * gb4.x + xb.y * gb4.y + xb.z * gb4.z + xb.w * gb4.w;
        sums[r][3] = xa.x * oa.x + xa.y * oa.y + xa.z * oa.z + xa.w * oa.w
                   + xb.x * ob.x + xb.y * ob.y + xb.z * ob.z + xb.w * ob.w;
    }
#pragma unroll
    for (int r = 0; r < 8; ++r)
#pragma unroll
        for (int g = 0; g < 4; ++g)
            for (int off = 32; off; off >>= 1)
                sums[r][g] += __shfl_xor(sums[r][g], off);

    if (lane < 4) {
        const float bias = (lane == 0) ? bfp[0] : (lane == 1) ? bip[0]
                         : (lane == 2) ? bgp[0] : bop[0];
#pragma unroll
        for (int r = 0; r < 8; ++r) {
            const float s = (lane == 0) ? sums[r][0] : (lane == 1) ? sums[r][1]
                          : (lane == 2) ? sums[r][2] : sums[r][3];
            st_rlx(((float*)&X4[rowbase + r]) + lane, (s + bias) * INV2PI);
        }
    }
    VMFENCE();
    __syncthreads();
    if (tid == 0)
        __hip_atomic_fetch_add(&cnt[gb >> 6], 1, __ATOMIC_RELAXED, AGENT);
}

extern "C" void kernel_launch(void* const* d_in, const int* in_sizes, int n_in,
                              void* d_out, int out_size, void* d_ws, size_t ws_size,
                              hipStream_t stream)
{
    const float* inp = (const float*)d_in[0];
    const float* Wf  = (const float*)d_in[1];
    const float* bfv = (const float*)d_in[2];
    const float* Pf  = (const float*)d_in[3];
    const float* Wi  = (const float*)d_in[4];
    const float* biv = (const float*)d_in[5];
    const float* Pi  = (const float*)d_in[6];
    const float* Wg  = (const float*)d_in[7];
    const float* bgv = (const float*)d_in[8];
    const float* Pg  = (const float*)d_in[9];
    const float* Wo  = (const float*)d_in[10];
    const float* bov = (const float*)d_in[11];
    const float* Po  = (const float*)d_in[12];

    float4* X4   = (float4*)d_ws;                     // NROWS + PF*BATCH
    float*  Hs   = (float*)(X4 + NROWS + PF * BATCH); // 32768
    float*  cfin = Hs + NROWS;                        // 128
    float*  gc   = cfin + BATCH;                      // 16
    int*    sync = (int*)(gc + 16);                   // qflag, hProg[2], cnt[16]
    int*    qflag = sync;
    int*    hProg = sync + 1;
    int*    cnt   = sync + 3;

    hipMemsetAsync(sync, 0, 19 * sizeof(int), stream);
    mega<<<GRID, 256, 0, stream>>>(inp, Wf, Wi, Wg, Wo,
                                   bfv, biv, bgv, bov,
                                   Pf, Pi, Pg, Po,
                                   (float4*)d_out,
                                   X4, Hs, cfin, gc, qflag, hProg, cnt);
}

// Round 13
// 54.909 us; speedup vs baseline: 1.8858x; 1.8858x over previous
//
#include <hip/hip_runtime.h>
#include <math.h>

#define T_STEPS 256
#define BATCH   128
#define DIMD    512
#define NROWS   (T_STEPS * BATCH)   // 32768
#define PF      16                  // prefetch depth (named-register pipeline)
#define WRITER_BLOCKS 258
#define GEMV_BLOCKS 2048            // 16 rows/block, 4 rows/wave

#define INV2PI  0.15915494309189535f
#define L2E     1.4426950408889634f
#define TWO_L2E 2.8853900817779268f

#define AGENT __HIP_MEMORY_SCOPE_AGENT

typedef float f32x4 __attribute__((ext_vector_type(4)));

#if __has_builtin(__builtin_amdgcn_sinf)
#define HW_SIN(x) __builtin_amdgcn_sinf(x)   // sin(2*pi*x), x in revolutions
#else
__device__ __forceinline__ float HW_SIN(float x) { return __sinf(x * 6.283185307179586f); }
#endif
#if __has_builtin(__builtin_amdgcn_exp2f)
#define EXP2(x) __builtin_amdgcn_exp2f(x)
#else
#define EXP2(x) exp2f(x)
#endif
#if __has_builtin(__builtin_amdgcn_rcpf)
#define RCP(x) __builtin_amdgcn_rcpf(x)
#else
#define RCP(x) (1.0f / (x))
#endif

// Agent-scope relaxed ops (sc-flagged; no wbl2/inv cache maintenance).
__device__ __forceinline__ void  st_rlx(float* p, float v) {
    __hip_atomic_store(p, v, __ATOMIC_RELAXED, AGENT);
}
__device__ __forceinline__ void  st_rlx_i(int* p, int v) {
    __hip_atomic_store(p, v, __ATOMIC_RELAXED, AGENT);
}
__device__ __forceinline__ int   ld_rlx_i(const int* p) {
    return __hip_atomic_load(p, __ATOMIC_RELAXED, AGENT);
}
#define VMFENCE() asm volatile("s_waitcnt vmcnt(0)" ::: "memory")
#define CFENCE()  asm volatile("" ::: "memory")

// ---------------------------------------------------------------------------
// prep: block 0 = qconsts (4 gates, one wave each); blocks 1.. = gemv
// (4 rows/wave). Pure producers; dispatch boundary publishes gc and X4.
// gc[4g+0]=scale*A, gc[4g+1]=scale*R, gc[4g+2]=phi_rev, gc[4g+3]=sumWh/2pi
// scale = -L2E (sigmoid f,i,o) or +2*L2E (tanh g).
// X4[t*B+b] = (dot + b0)/2pi  (phase folded in the scan at refill).
// ---------------------------------------------------------------------------
__global__ __launch_bounds__(256) void prep(
    const float* __restrict__ inp,
    const float* __restrict__ Wf, const float* __restrict__ Wi,
    const float* __restrict__ Wg, const float* __restrict__ Wo,
    const float* __restrict__ bfp, const float* __restrict__ bip,
    const float* __restrict__ bgp, const float* __restrict__ bop,
    const float* __restrict__ Pf, const float* __restrict__ Pi,
    const float* __restrict__ Pg, const float* __restrict__ Po,
    float* __restrict__ gc, int* __restrict__ hProg,
    float4* __restrict__ X4)
{
    const int bid  = blockIdx.x;
    const int wv   = threadIdx.x >> 6;
    const int lane = threadIdx.x & 63;

    if (bid == 0) {
        // ================= qconsts =================
        if (threadIdx.x == 0) { hProg[0] = 0; hProg[1] = 0; }
        const int g = wv;
        const float* P = (g == 0) ? Pf : (g == 1) ? Pi : (g == 2) ? Pg : Po;
        const float* W = (g == 0) ? Wf : (g == 1) ? Wi : (g == 2) ? Wg : Wo;

        __shared__ float s0r[4][256], s0i[4][256], s1r[4][256], s1i[4][256];

#pragma unroll
        for (int j = 0; j < 4; ++j) {
            const int k = lane + 64 * j;
            s0r[g][k] = (k == 0)   ? 1.0f : 0.0f;  s0i[g][k] = 0.0f;
            s1r[g][k] = (k == 128) ? 1.0f : 0.0f;  s1i[g][k] = 0.0f;
        }
        __syncthreads();

        for (int l = 0; l < 2; ++l) {
            for (int w = 0; w < 8; ++w) {
                const float phi = P[l * 24 + w * 3 + 0];
                const float th  = P[l * 24 + w * 3 + 1];
                const float om  = P[l * 24 + w * 3 + 2];
                float sh, chh; __sincosf(0.5f * th, &sh, &chh);
                float sp, cp;  __sincosf(0.5f * (phi + om), &sp, &cp);
                float sm, cm;  __sincosf(0.5f * (phi - om), &sm, &cm);
                const float m00r =  cp * chh, m00i = -sp * chh;
                const float m01r = -cm * sh,  m01i = -sm * sh;
                const float m10r =  cm * sh,  m10i = -sm * sh;
                const float m11r =  cp * chh, m11i =  sp * chh;

                const int shift = 7 - w;
                const int mask  = 1 << shift;

                float n0r[4], n0i[4], n1r[4], n1i[4];
#pragma unroll
                for (int j = 0; j < 4; ++j) {
                    const int k  = lane + 64 * j;
                    const int bit = (k >> shift) & 1;
                    const int i0 = k & ~mask, i1 = k | mask;
                    const float a0r = s0r[g][i0], a0i = s0i[g][i0];
                    const float a1r = s0r[g][i1], a1i = s0i[g][i1];
                    const float b0r = s1r[g][i0], b0i = s1i[g][i0];
                    const float b1r = s1r[g][i1], b1i = s1i[g][i1];
                    const float mr0 = bit ? m10r : m00r, mi0 = bit ? m10i : m00i;
                    const float mr1 = bit ? m11r : m01r, mi1 = bit ? m11i : m01i;
                    n0r[j] = mr0 * a0r - mi0 * a0i + mr1 * a1r - mi1 * a1i;
                    n0i[j] = mr0 * a0i + mi0 * a0r + mr1 * a1i + mi1 * a1r;
                    n1r[j] = mr0 * b0r - mi0 * b0i + mr1 * b1r - mi1 * b1i;
                    n1i[j] = mr0 * b0i + mi0 * b0r + mr1 * b1i + mi1 * b1r;
                }
                __syncthreads();
#pragma unroll
                for (int j = 0; j < 4; ++j) {
                    const int k = lane + 64 * j;
                    s0r[g][k] = n0r[j]; s0i[g][k] = n0i[j];
                    s1r[g][k] = n1r[j]; s1i[g][k] = n1i[j];
                }
                __syncthreads();
            }
            // CNOT chain permutation
            float n0r[4], n0i[4], n1r[4], n1i[4];
#pragma unroll
            for (int j = 0; j < 4; ++j) {
                int src = lane + 64 * j;
                for (int w = 6; w >= 0; --w) {
                    const int cb = (src >> (7 - w)) & 1;
                    src ^= cb << (6 - w);
                }
                n0r[j] = s0r[g][src]; n0i[j] = s0i[g][src];
                n1r[j] = s1r[g][src]; n1i[j] = s1i[g][src];
            }
            __syncthreads();
#pragma unroll
            for (int j = 0; j < 4; ++j) {
                const int k = lane + 64 * j;
                s0r[g][k] = n0r[j]; s0i[g][k] = n0i[j];
                s1r[g][k] = n1r[j]; s1i[g][k] = n1i[j];
            }
            __syncthreads();
        }

        float t00 = 0, t11 = 0, t01 = 0;
#pragma unroll
        for (int j = 0; j < 4; ++j) {
            const int k = lane + 64 * j;
            const float z = (k < 128) ? 1.0f : -1.0f;
            t00 += z * (s0r[g][k] * s0r[g][k] + s0i[g][k] * s0i[g][k]);
            t11 += z * (s1r[g][k] * s1r[g][k] + s1i[g][k] * s1i[g][k]);
            t01 += z * (s0i[g][k] * s1r[g][k] - s0r[g][k] * s1i[g][k]);
        }
        float tsw = 0;
#pragma unroll
        for (int j = 0; j < 8; ++j) tsw += W[512 + lane + 64 * j];

        for (int off = 32; off; off >>= 1) {
            t00 += __shfl_xor(t00, off);
            t11 += __shfl_xor(t11, off);
            t01 += __shfl_xor(t01, off);
            tsw += __shfl_xor(tsw, off);
        }
        if (lane == 0) {
            const float A  = 0.5f * (t00 + t11);
            const float Bc = 0.5f * (t00 - t11);
            const float Bs = -t01;
            const float R  = sqrtf(Bc * Bc + Bs * Bs);
            const float ph = atan2f(Bc, Bs) * INV2PI;
            const float sc = (g == 2) ? TWO_L2E : -L2E;
            gc[4 * g + 0] = sc * A;
            gc[4 * g + 1] = sc * R;
            gc[4 * g + 2] = ph;
            gc[4 * g + 3] = tsw * INV2PI;
        }
        return;
    }

    // ================= gemv: 4 rows per wave =================
    const int rowbase = (bid - 1) * 16 + wv * 4;

    const float4* wfp = (const float4*)Wf;
    const float4* wip = (const float4*)Wi;
    const float4* wgp = (const float4*)Wg;
    const float4* wop = (const float4*)Wo;
    const float4 fa = wfp[lane], fb = wfp[lane + 64];
    const float4 ia = wip[lane], ib = wip[lane + 64];
    const float4 ga = wgp[lane], gb = wgp[lane + 64];
    const float4 oa = wop[lane], ob = wop[lane + 64];

    const float4* xr = (const float4*)(inp + (size_t)rowbase * DIMD);
    float sums[4][4];   // [row][gate]
#pragma unroll
    for (int r = 0; r < 4; ++r) {
        const float4 xa = xr[r * 128 + lane];
        const float4 xb = xr[r * 128 + lane + 64];
        sums[r][0] = xa.x * fa.x + xa.y * fa.y + xa.z * fa.z + xa.w * fa.w
                   + xb.x * fb.x + xb.y * fb.y + xb.z * fb.z + xb.w * fb.w;
        sums[r][1] = xa.x * ia.x + xa.y * ia.y + xa.z * ia.z + xa.w * ia.w
                   + xb.x * ib.x + xb.y * ib.y + xb.z * ib.z + xb.w * ib.w;
        sums[r][2] = xa.x * ga.x + xa.y * ga.y + xa.z * ga.z + xa.w * ga.w
                   + xb.x * gb.x + xb.y * gb.y + xb.z * gb.z + xb.w * gb.w;
        sums[r][3] = xa.x * oa.x + xa.y * oa.y + xa.z * oa.z + xa.w * oa.w
                   + xb.x * ob.x + xb.y * ob.y + xb.z * ob.z + xb.w * ob.w;
    }
#pragma unroll
    for (int r = 0; r < 4; ++r)
#pragma unroll
        for (int g = 0; g < 4; ++g)
            for (int off = 32; off; off >>= 1)
                sums[r][g] += __shfl_xor(sums[r][g], off);

    if (lane == 0) {
        const float b0f = bfp[0], b0i = bip[0], b0g = bgp[0], b0o = bop[0];
#pragma unroll
        for (int r = 0; r < 4; ++r) {
            X4[rowbase + r] = make_float4((sums[r][0] + b0f) * INV2PI,
                                          (sums[r][1] + b0i) * INV2PI,
                                          (sums[r][2] + b0g) * INV2PI,
                                          (sums[r][3] + b0o) * INV2PI);
        }
    }
}

// ---------------------------------------------------------------------------
// Fused scan + broadcast. Grid 259 x 256.
// Block 0 (waves 0,1): recurrence, 64 chains/wave. PF=16 rolling prefetch in
// SIXTEEN NAMED float4 locals (no arrays -> regalloc cannot demote to
// scratch; R8/R9's VGPR_Count=44 proved p[16] was NOT in registers).
// Publishes hProg[wv] at t=64/128/192/256. Blocks 1..258: writers.
// ---------------------------------------------------------------------------
__global__ __launch_bounds__(256, 1) void scan_write(
    const float4* __restrict__ X4, const float* __restrict__ gc,
    float* __restrict__ Hs, float* __restrict__ cfin,
    float4* __restrict__ out4, int* __restrict__ hProg)
{
    const int bid  = blockIdx.x;
    const int wv   = threadIdx.x >> 6;
    const int lane = threadIdx.x & 63;

    if (bid == 0) {
        // ---------------- scan ----------------
        if (threadIdx.x >= BATCH) return;
        const int b = threadIdx.x;

        const float Af = gc[0],  Rf = gc[1],  phf = gc[2],  swf = gc[3];
        const float Ai = gc[4],  Ri = gc[5],  phi_ = gc[6], swi = gc[7];
        const float Ag = gc[8],  Rg = gc[9],  phg = gc[10], swg = gc[11];
        const float Ao = gc[12], Ro = gc[13], pho = gc[14], swo = gc[15];

        float4 p0, p1, p2, p3, p4, p5, p6, p7,
               p8, p9, p10, p11, p12, p13, p14, p15;

#define LOADP(J, P) { const float4 v_ = X4[(J) * BATCH + b];                 \
        P = make_float4(v_.x + phf, v_.y + phi_, v_.z + phg, v_.w + pho); }
        LOADP(0, p0)   LOADP(1, p1)   LOADP(2, p2)   LOADP(3, p3)
        LOADP(4, p4)   LOADP(5, p5)   LOADP(6, p6)   LOADP(7, p7)
        LOADP(8, p8)   LOADP(9, p9)   LOADP(10, p10) LOADP(11, p11)
        LOADP(12, p12) LOADP(13, p13) LOADP(14, p14) LOADP(15, p15)
#undef LOADP

        float c = 0.0f, h = 0.0f;
        for (int tb = 0; tb < T_STEPS; tb += PF) {
#define STEP(J, P) {                                                         \
            const float4 xv = P;                                             \
            { const float4 v_ = X4[(tb + (J) + PF) * BATCH + b];             \
              P = make_float4(v_.x + phf, v_.y + phi_,                       \
                              v_.z + phg, v_.w + pho); }                     \
            const float thf = fmaf(h, swf, xv.x);                            \
            const float thi = fmaf(h, swi, xv.y);                            \
            const float thg = fmaf(h, swg, xv.z);                            \
            const float tho = fmaf(h, swo, xv.w);                            \
            const float ef = EXP2(fmaf(Rf, HW_SIN(thf), Af));                \
            const float ei = EXP2(fmaf(Ri, HW_SIN(thi), Ai));                \
            const float eg = EXP2(fmaf(Rg, HW_SIN(thg), Ag));                \
            const float eo = EXP2(fmaf(Ro, HW_SIN(tho), Ao));                \
            const float Ff = ef + 1.0f, Fi = ei + 1.0f;                      \
            const float Fg = eg + 1.0f, Fo = eo + 1.0f;                      \
            const float FiFg = Fi * Fg;                                      \
            const float num  = fmaf(c, FiFg, (eg - 1.0f) * Ff);              \
            c = num * RCP(Ff * FiFg);                                        \
            const float ec = EXP2(c * TWO_L2E);                              \
            h = (ec - 1.0f) * RCP(Fo * (ec + 1.0f));                         \
            st_rlx(&Hs[(tb + (J)) * BATCH + b], h); }
            STEP(0, p0)   STEP(1, p1)   STEP(2, p2)   STEP(3, p3)
            STEP(4, p4)   STEP(5, p5)   STEP(6, p6)   STEP(7, p7)
            STEP(8, p8)   STEP(9, p9)   STEP(10, p10) STEP(11, p11)
            STEP(12, p12) STEP(13, p13) STEP(14, p14) STEP(15, p15)
#undef STEP
            if (tb == T_STEPS - PF) st_rlx(&cfin[b], c);
            if (((tb + PF) & 63) == 0) {   // publish at t = 64,128,192,256
                VMFENCE();
                if (lane == 0) st_rlx_i(&hProg[wv], tb + PF);
            }
        }
        return;
    }

    // ---------------- writers ----------------
    const int t  = bid - 1;           // 0..257 (256=hx, 257=cx)
    const int qd = wv;                // quarter: b in [qd*32, qd*32+32)
    const int pidx = (qd < 2) ? 0 : 1;
    const int need = (t < 256) ? ((t >> 6) + 1) << 6 : 256;

    int cur = ld_rlx_i(&hProg[pidx]);
    while (cur < need) {
        int loops = ((need - cur) >> 5) + 1;   // ~1 sleep-pair per 32 steps
        for (int s = 0; s < loops; ++s) {
            __builtin_amdgcn_s_sleep(32);
            __builtin_amdgcn_s_sleep(32);
        }
        cur = ld_rlx_i(&hProg[pidx]);
    }
    CFENCE();

    const float* src = (t == 257) ? cfin : (Hs + ((t >= 256 ? 255 : t) * BATCH));
    const float hv = src[qd * 32 + (lane & 31)];

    size_t base = (t < 256) ? ((size_t)t * 16384)
                : (t == 256 ? (size_t)4194304 : (size_t)4210688);
    base += (size_t)qd * 4096;
#pragma unroll 8
    for (int j = 0; j < 64; ++j) {
        const float v = __shfl(hv, j >> 1);
        const f32x4 val = {v, v, v, v};
        __builtin_nontemporal_store(val, (f32x4*)(out4 + base + j * 64 + lane));
    }
}

extern "C" void kernel_launch(void* const* d_in, const int* in_sizes, int n_in,
                              void* d_out, int out_size, void* d_ws, size_t ws_size,
                              hipStream_t stream)
{
    const float* inp = (const float*)d_in[0];
    const float* Wf  = (const float*)d_in[1];
    const float* bfv = (const float*)d_in[2];
    const float* Pf  = (const float*)d_in[3];
    const float* Wi  = (const float*)d_in[4];
    const float* biv = (const float*)d_in[5];
    const float* Pi  = (const float*)d_in[6];
    const float* Wg  = (const float*)d_in[7];
    const float* bgv = (const float*)d_in[8];
    const float* Pg  = (const float*)d_in[9];
    const float* Wo  = (const float*)d_in[10];
    const float* bov = (const float*)d_in[11];
    const float* Po  = (const float*)d_in[12];

    float4* X4   = (float4*)d_ws;                     // NROWS + PF*BATCH
    float*  Hs   = (float*)(X4 + NROWS + PF * BATCH); // 32768
    float*  cfin = Hs + NROWS;                        // 128
    float*  gc   = cfin + BATCH;                      // 16
    int*    hProg = (int*)(gc + 16);                  // 2

    prep<<<1 + GEMV_BLOCKS, 256, 0, stream>>>(inp, Wf, Wi, Wg, Wo,
                                              bfv, biv, bgv, bov,
                                              Pf, Pi, Pg, Po,
                                              gc, hProg, X4);
    scan_write<<<1 + WRITER_BLOCKS, 256, 0, stream>>>(X4, gc, Hs, cfin,
                                                      (float4*)d_out, hProg);
}

// Round 14
// 54.875 us; speedup vs baseline: 1.8870x; 1.0006x over previous
//
#include <hip/hip_runtime.h>
#include <math.h>

#define T_STEPS 256
#define BATCH   128
#define DIMD    512
#define NROWS   (T_STEPS * BATCH)   // 32768
#define PF      16                  // chunk size (LDS staging granularity)
#define NCHUNK  (T_STEPS / PF)      // 16
#define WRITER_BLOCKS 258
#define GEMV_BLOCKS 2048            // 16 rows/block, 4 rows/wave

#define INV2PI  0.15915494309189535f
#define L2E     1.4426950408889634f
#define TWO_L2E 2.8853900817779268f

#define AGENT __HIP_MEMORY_SCOPE_AGENT

typedef float f32x4 __attribute__((ext_vector_type(4)));

#if __has_builtin(__builtin_amdgcn_sinf)
#define HW_SIN(x) __builtin_amdgcn_sinf(x)   // sin(2*pi*x), x in revolutions
#else
__device__ __forceinline__ float HW_SIN(float x) { return __sinf(x * 6.283185307179586f); }
#endif
#if __has_builtin(__builtin_amdgcn_exp2f)
#define EXP2(x) __builtin_amdgcn_exp2f(x)
#else
#define EXP2(x) exp2f(x)
#endif
#if __has_builtin(__builtin_amdgcn_rcpf)
#define RCP(x) __builtin_amdgcn_rcpf(x)
#else
#define RCP(x) (1.0f / (x))
#endif

// Agent-scope relaxed ops (sc-flagged; no wbl2/inv cache maintenance).
__device__ __forceinline__ void  st_rlx(float* p, float v) {
    __hip_atomic_store(p, v, __ATOMIC_RELAXED, AGENT);
}
__device__ __forceinline__ void  st_rlx_i(int* p, int v) {
    __hip_atomic_store(p, v, __ATOMIC_RELAXED, AGENT);
}
__device__ __forceinline__ int   ld_rlx_i(const int* p) {
    return __hip_atomic_load(p, __ATOMIC_RELAXED, AGENT);
}
#define CFENCE()  asm volatile("" ::: "memory")

// ---------------------------------------------------------------------------
// prep: block 0 = qconsts (4 gates, one wave each); blocks 1.. = gemv
// (4 rows/wave). Pure producers; dispatch boundary publishes gc and X4.
// gc[4g+0]=scale*A, gc[4g+1]=scale*R, gc[4g+2]=phi_rev, gc[4g+3]=sumWh/2pi
// scale = -L2E (sigmoid f,i,o) or +2*L2E (tanh g).
// X4[t*B+b] = (dot + b0)/2pi  (phase folded by the staging waves).
// ---------------------------------------------------------------------------
__global__ __launch_bounds__(256) void prep(
    const float* __restrict__ inp,
    const float* __restrict__ Wf, const float* __restrict__ Wi,
    const float* __restrict__ Wg, const float* __restrict__ Wo,
    const float* __restrict__ bfp, const float* __restrict__ bip,
    const float* __restrict__ bgp, const float* __restrict__ bop,
    const float* __restrict__ Pf, const float* __restrict__ Pi,
    const float* __restrict__ Pg, const float* __restrict__ Po,
    float* __restrict__ gc, int* __restrict__ hProg,
    float4* __restrict__ X4)
{
    const int bid  = blockIdx.x;
    const int wv   = threadIdx.x >> 6;
    const int lane = threadIdx.x & 63;

    if (bid == 0) {
        // ================= qconsts =================
        if (threadIdx.x == 0) { hProg[0] = 0; hProg[1] = 0; }
        const int g = wv;
        const float* P = (g == 0) ? Pf : (g == 1) ? Pi : (g == 2) ? Pg : Po;
        const float* W = (g == 0) ? Wf : (g == 1) ? Wi : (g == 2) ? Wg : Wo;

        __shared__ float s0r[4][256], s0i[4][256], s1r[4][256], s1i[4][256];

#pragma unroll
        for (int j = 0; j < 4; ++j) {
            const int k = lane + 64 * j;
            s0r[g][k] = (k == 0)   ? 1.0f : 0.0f;  s0i[g][k] = 0.0f;
            s1r[g][k] = (k == 128) ? 1.0f : 0.0f;  s1i[g][k] = 0.0f;
        }
        __syncthreads();

        for (int l = 0; l < 2; ++l) {
            for (int w = 0; w < 8; ++w) {
                const float phi = P[l * 24 + w * 3 + 0];
                const float th  = P[l * 24 + w * 3 + 1];
                const float om  = P[l * 24 + w * 3 + 2];
                float sh, chh; __sincosf(0.5f * th, &sh, &chh);
                float sp, cp;  __sincosf(0.5f * (phi + om), &sp, &cp);
                float sm, cm;  __sincosf(0.5f * (phi - om), &sm, &cm);
                const float m00r =  cp * chh, m00i = -sp * chh;
                const float m01r = -cm * sh,  m01i = -sm * sh;
                const float m10r =  cm * sh,  m10i = -sm * sh;
                const float m11r =  cp * chh, m11i =  sp * chh;

                const int shift = 7 - w;
                const int mask  = 1 << shift;

                float n0r[4], n0i[4], n1r[4], n1i[4];
#pragma unroll
                for (int j = 0; j < 4; ++j) {
                    const int k  = lane + 64 * j;
                    const int bit = (k >> shift) & 1;
                    const int i0 = k & ~mask, i1 = k | mask;
                    const float a0r = s0r[g][i0], a0i = s0i[g][i0];
                    const float a1r = s0r[g][i1], a1i = s0i[g][i1];
                    const float b0r = s1r[g][i0], b0i = s1i[g][i0];
                    const float b1r = s1r[g][i1], b1i = s1i[g][i1];
                    const float mr0 = bit ? m10r : m00r, mi0 = bit ? m10i : m00i;
                    const float mr1 = bit ? m11r : m01r, mi1 = bit ? m11i : m01i;
                    n0r[j] = mr0 * a0r - mi0 * a0i + mr1 * a1r - mi1 * a1i;
                    n0i[j] = mr0 * a0i + mi0 * a0r + mr1 * a1i + mi1 * a1r;
                    n1r[j] = mr0 * b0r - mi0 * b0i + mr1 * b1r - mi1 * b1i;
                    n1i[j] = mr0 * b0i + mi0 * b0r + mr1 * b1i + mi1 * b1r;
                }
                __syncthreads();
#pragma unroll
                for (int j = 0; j < 4; ++j) {
                    const int k = lane + 64 * j;
                    s0r[g][k] = n0r[j]; s0i[g][k] = n0i[j];
                    s1r[g][k] = n1r[j]; s1i[g][k] = n1i[j];
                }
                __syncthreads();
            }
            // CNOT chain permutation
            float n0r[4], n0i[4], n1r[4], n1i[4];
#pragma unroll
            for (int j = 0; j < 4; ++j) {
                int src = lane + 64 * j;
                for (int w = 6; w >= 0; --w) {
                    const int cb = (src >> (7 - w)) & 1;
                    src ^= cb << (6 - w);
                }
                n0r[j] = s0r[g][src]; n0i[j] = s0i[g][src];
                n1r[j] = s1r[g][src]; n1i[j] = s1i[g][src];
            }
            __syncthreads();
#pragma unroll
            for (int j = 0; j < 4; ++j) {
                const int k = lane + 64 * j;
                s0r[g][k] = n0r[j]; s0i[g][k] = n0i[j];
                s1r[g][k] = n1r[j]; s1i[g][k] = n1i[j];
            }
            __syncthreads();
        }

        float t00 = 0, t11 = 0, t01 = 0;
#pragma unroll
        for (int j = 0; j < 4; ++j) {
            const int k = lane + 64 * j;
            const float z = (k < 128) ? 1.0f : -1.0f;
            t00 += z * (s0r[g][k] * s0r[g][k] + s0i[g][k] * s0i[g][k]);
            t11 += z * (s1r[g][k] * s1r[g][k] + s1i[g][k] * s1i[g][k]);
            t01 += z * (s0i[g][k] * s1r[g][k] - s0r[g][k] * s1i[g][k]);
        }
        float tsw = 0;
#pragma unroll
        for (int j = 0; j < 8; ++j) tsw += W[512 + lane + 64 * j];

        for (int off = 32; off; off >>= 1) {
            t00 += __shfl_xor(t00, off);
            t11 += __shfl_xor(t11, off);
            t01 += __shfl_xor(t01, off);
            tsw += __shfl_xor(tsw, off);
        }
        if (lane == 0) {
            const float A  = 0.5f * (t00 + t11);
            const float Bc = 0.5f * (t00 - t11);
            const float Bs = -t01;
            const float R  = sqrtf(Bc * Bc + Bs * Bs);
            const float ph = atan2f(Bc, Bs) * INV2PI;
            const float sc = (g == 2) ? TWO_L2E : -L2E;
            gc[4 * g + 0] = sc * A;
            gc[4 * g + 1] = sc * R;
            gc[4 * g + 2] = ph;
            gc[4 * g + 3] = tsw * INV2PI;
        }
        return;
    }

    // ================= gemv: 4 rows per wave =================
    const int rowbase = (bid - 1) * 16 + wv * 4;

    const float4* wfp = (const float4*)Wf;
    const float4* wip = (const float4*)Wi;
    const float4* wgp = (const float4*)Wg;
    const float4* wop = (const float4*)Wo;
    const float4 fa = wfp[lane], fb = wfp[lane + 64];
    const float4 ia = wip[lane], ib = wip[lane + 64];
    const float4 ga = wgp[lane], gb = wgp[lane + 64];
    const float4 oa = wop[lane], ob = wop[lane + 64];

    const float4* xr = (const float4*)(inp + (size_t)rowbase * DIMD);
    float sums[4][4];   // [row][gate]
#pragma unroll
    for (int r = 0; r < 4; ++r) {
        const float4 xa = xr[r * 128 + lane];
        const float4 xb = xr[r * 128 + lane + 64];
        sums[r][0] = xa.x * fa.x + xa.y * fa.y + xa.z * fa.z + xa.w * fa.w
                   + xb.x * fb.x + xb.y * fb.y + xb.z * fb.z + xb.w * fb.w;
        sums[r][1] = xa.x * ia.x + xa.y * ia.y + xa.z * ia.z + xa.w * ia.w
                   + xb.x * ib.x + xb.y * ib.y + xb.z * ib.z + xb.w * ib.w;
        sums[r][2] = xa.x * ga.x + xa.y * ga.y + xa.z * ga.z + xa.w * ga.w
                   + xb.x * gb.x + xb.y * gb.y + xb.z * gb.z + xb.w * gb.w;
        sums[r][3] = xa.x * oa.x + xa.y * oa.y + xa.z * oa.z + xa.w * oa.w
                   + xb.x * ob.x + xb.y * ob.y + xb.z * ob.z + xb.w * ob.w;
    }
#pragma unroll
    for (int r = 0; r < 4; ++r)
#pragma unroll
        for (int g = 0; g < 4; ++g)
            for (int off = 32; off; off >>= 1)
                sums[r][g] += __shfl_xor(sums[r][g], off);

    if (lane == 0) {
        const float b0f = bfp[0], b0i = bip[0], b0g = bgp[0], b0o = bop[0];
#pragma unroll
        for (int r = 0; r < 4; ++r) {
            X4[rowbase + r] = make_float4((sums[r][0] + b0f) * INV2PI,
                                          (sums[r][1] + b0i) * INV2PI,
                                          (sums[r][2] + b0g) * INV2PI,
                                          (sums[r][3] + b0o) * INV2PI);
        }
    }
}

// ---------------------------------------------------------------------------
// Fused scan + broadcast. Grid 259 x 256.
// Block 0: producer/consumer role split. Waves 0-1 (tid<128) = scan
// consumers reading X-chunks from double-buffered LDS (ds_read, 2-deep
// named-register pipeline). Waves 2-3 = producers staging chunk k+1 from
// global into LDS (phases pre-added) — they absorb ALL global latency,
// which the compiler provably refused to pipeline in consumer code
// (R13: VGPR_Count=44 despite 16 named float4 locals).
// __syncthreads per chunk = handoff; publish hProg[0] after barrier.
// Blocks 1..258: writers (deficit-proportional sleep, NT output stores).
// ---------------------------------------------------------------------------
__global__ __launch_bounds__(256) void scan_write(
    const float4* __restrict__ X4, const float* __restrict__ gc,
    float* __restrict__ Hs, float* __restrict__ cfin,
    float4* __restrict__ out4, int* __restrict__ hProg)
{
    const int bid  = blockIdx.x;
    const int tid  = threadIdx.x;
    const int wv   = tid >> 6;
    const int lane = tid & 63;

    if (bid == 0) {
        __shared__ float4 xbuf[2][PF][BATCH];   // 64 KB double buffer

        const float phf = gc[2], phi_ = gc[6], phg = gc[10], pho = gc[14];

        if (tid >= BATCH) {
            // -------- producer prologue: stage chunk 0 into buf 0 --------
            const int b = tid - BATCH;
#pragma unroll
            for (int j = 0; j < PF; ++j) {
                const float4 v = X4[j * BATCH + b];
                xbuf[0][j][b] = make_float4(v.x + phf, v.y + phi_,
                                            v.z + phg, v.w + pho);
            }
        }
        __syncthreads();

        const float Af = gc[0],  Rf = gc[1],  swf = gc[3];
        const float Ai = gc[4],  Ri = gc[5],  swi = gc[7];
        const float Ag = gc[8],  Rg = gc[9],  swg = gc[11];
        const float Ao = gc[12], Ro = gc[13], swo = gc[15];

        float c = 0.0f, h = 0.0f;
        for (int k = 0; k < NCHUNK; ++k) {
            const int tb = k * PF;
            if (tid >= BATCH) {
                // -------- producer: stage chunk k+1 (pad covers k=15) ----
                const int b  = tid - BATCH;
                const int nb = (k + 1) & 1;
#pragma unroll
                for (int j = 0; j < PF; ++j) {
                    const float4 v = X4[(tb + PF + j) * BATCH + b];
                    xbuf[nb][j][b] = make_float4(v.x + phf, v.y + phi_,
                                                 v.z + phg, v.w + pho);
                }
            } else {
                // -------- consumer: 16 steps from xbuf[k&1] --------------
                const int b  = tid;
                const int cb = k & 1;
                float4 xv = xbuf[cb][0][b];
#pragma unroll
                for (int j = 0; j < PF; ++j) {
                    float4 nx;
                    if (j < PF - 1) nx = xbuf[cb][j + 1][b];  // 2-deep pipe
                    const float thf = fmaf(h, swf, xv.x);
                    const float thi = fmaf(h, swi, xv.y);
                    const float thg = fmaf(h, swg, xv.z);
                    const float tho = fmaf(h, swo, xv.w);
                    const float ef = EXP2(fmaf(Rf, HW_SIN(thf), Af));
                    const float ei = EXP2(fmaf(Ri, HW_SIN(thi), Ai));
                    const float eg = EXP2(fmaf(Rg, HW_SIN(thg), Ag));
                    const float eo = EXP2(fmaf(Ro, HW_SIN(tho), Ao));
                    const float Ff = ef + 1.0f, Fi = ei + 1.0f;
                    const float Fg = eg + 1.0f, Fo = eo + 1.0f;
                    const float FiFg = Fi * Fg;
                    const float num  = fmaf(c, FiFg, (eg - 1.0f) * Ff);
                    c = num * RCP(Ff * FiFg);                  // single rcp
                    const float ec = EXP2(c * TWO_L2E);
                    h = (ec - 1.0f) * RCP(Fo * (ec + 1.0f));   // o*tanh(c)
                    st_rlx(&Hs[(tb + j) * BATCH + b], h);
                    xv = nx;
                }
                if (k == NCHUNK - 1) st_rlx(&cfin[b], c);
            }
            __syncthreads();   // handoff; each wave drains its own vm ops
            if ((k & 3) == 3 && tid == 0)
                st_rlx_i(&hProg[0], tb + PF);   // t = 64,128,192,256
        }
        return;
    }

    // ---------------- writers ----------------
    const int t  = bid - 1;           // 0..257 (256=hx, 257=cx)
    const int qd = wv;                // quarter: b in [qd*32, qd*32+32)
    const int need = (t < 256) ? ((t >> 6) + 1) << 6 : 256;

    int cur = ld_rlx_i(&hProg[0]);
    while (cur < need) {
        int loops = ((need - cur) >> 5) + 1;   // ~1 sleep-pair per 32 steps
        for (int s = 0; s < loops; ++s) {
            __builtin_amdgcn_s_sleep(32);
            __builtin_amdgcn_s_sleep(32);
        }
        cur = ld_rlx_i(&hProg[0]);
    }
    CFENCE();

    const float* src = (t == 257) ? cfin : (Hs + ((t >= 256 ? 255 : t) * BATCH));
    const float hv = src[qd * 32 + (lane & 31)];

    size_t base = (t < 256) ? ((size_t)t * 16384)
                : (t == 256 ? (size_t)4194304 : (size_t)4210688);
    base += (size_t)qd * 4096;
#pragma unroll 8
    for (int j = 0; j < 64; ++j) {
        const float v = __shfl(hv, j >> 1);
        const f32x4 val = {v, v, v, v};
        __builtin_nontemporal_store(val, (f32x4*)(out4 + base + j * 64 + lane));
    }
}

extern "C" void kernel_launch(void* const* d_in, const int* in_sizes, int n_in,
                              void* d_out, int out_size, void* d_ws, size_t ws_size,
                              hipStream_t stream)
{
    const float* inp = (const float*)d_in[0];
    const float* Wf  = (const float*)d_in[1];
    const float* bfv = (const float*)d_in[2];
    const float* Pf  = (const float*)d_in[3];
    const float* Wi  = (const float*)d_in[4];
    const float* biv = (const float*)d_in[5];
    const float* Pi  = (const float*)d_in[6];
    const float* Wg  = (const float*)d_in[7];
    const float* bgv = (const float*)d_in[8];
    const float* Pg  = (const float*)d_in[9];
    const float* Wo  = (const float*)d_in[10];
    const float* bov = (const float*)d_in[11];
    const float* Po  = (const float*)d_in[12];

    float4* X4   = (float4*)d_ws;                     // NROWS + PF*BATCH
    float*  Hs   = (float*)(X4 + NROWS + PF * BATCH); // 32768
    float*  cfin = Hs + NROWS;                        // 128
    float*  gc   = cfin + BATCH;                      // 16
    int*    hProg = (int*)(gc + 16);                  // 2

    prep<<<1 + GEMV_BLOCKS, 256, 0, stream>>>(inp, Wf, Wi, Wg, Wo,
                                              bfv, biv, bgv, bov,
                                              Pf, Pi, Pg, Po,
                                              gc, hProg, X4);
    scan_write<<<1 + WRITER_BLOCKS, 256, 0, stream>>>(X4, gc, Hs, cfin,
                                                      (float4*)d_out, hProg);
}